// Round 6
// baseline (221.426 us; speedup 1.0000x reference)
//
#include <hip/hip_runtime.h>
#include <math.h>

#define BATCH 128
#define NCI 768
#define NCO 64
#define DIN 8
#define DOUT 16

typedef __attribute__((ext_vector_type(8))) short bfrag;    // 8 bf16 = 4 VGPR
typedef __attribute__((ext_vector_type(4))) float f32x4;    // 16x16 accumulator
typedef __attribute__((ext_vector_type(16))) float f32x16;  // 32x32 accumulator

// split 8 f32 into bf16 hi (truncation) + bf16 lo (truncation of remainder).
// x = hi + lo with |err| ~ 2^-16 |x|; 3-term MFMA (hh + hl + lh) ~ fp32 precision.
__device__ __forceinline__ void split8(const float* x, bfrag& hi, bfrag& lo) {
    #pragma unroll
    for (int j = 0; j < 8; ++j) {
        unsigned xb = __float_as_uint(x[j]);
        unsigned hb = xb & 0xffff0000u;
        float lf = x[j] - __uint_as_float(hb);
        hi[j] = (short)(xb >> 16);
        lo[j] = (short)(__float_as_uint(lf) >> 16);
    }
}

// ---------------- conv1: x(128,3,32,42) w(32,3,6,6) stride 3 -> h1(128,32,9,13), relu
__global__ __launch_bounds__(256) void conv1_kernel(
    const float* __restrict__ x, const float* __restrict__ w,
    const float* __restrict__ bias, float* __restrict__ h1) {
    __shared__ float wl[32 * 3 * 36];
    for (int i = threadIdx.x; i < 3456; i += 256) wl[i] = w[i];
    __syncthreads();
    int idx = blockIdx.x * 256 + threadIdx.x;
    const int total = BATCH * 32 * 9 * 13;
    if (idx >= total) return;
    int ow = idx % 13; int t = idx / 13;
    int oh = t % 9; t /= 9;
    int oc = t % 32; int b = t / 32;
    float acc = bias[oc];
    const float* xb = x + (size_t)b * 3 * 32 * 42;
    #pragma unroll
    for (int ic = 0; ic < 3; ++ic) {
        const float* xc = xb + ic * 32 * 42 + (oh * 3) * 42 + ow * 3;
        const float* wc = wl + (oc * 3 + ic) * 36;
        #pragma unroll
        for (int kh = 0; kh < 6; ++kh)
            #pragma unroll
            for (int kw = 0; kw < 6; ++kw)
                acc += xc[kh * 42 + kw] * wc[kh * 6 + kw];
    }
    h1[idx] = fmaxf(acc, 0.f);
}

// ---------------- im2col for primary-caps conv: B2[ko][n][j], ko=K-octet (36), n=(b,s) (3072)
__global__ __launch_bounds__(256) void im2col_kernel(
    const float* __restrict__ h1, float* __restrict__ B2) {
    int idx = blockIdx.x * 256 + threadIdx.x;
    if (idx >= 36 * 3072) return;
    int n = idx % 3072, ko = idx / 3072;
    int b = n / 24, s = n % 24, h = s / 6, w = s % 6;
    const float* hb = h1 + (size_t)b * 3744 + (2 * h) * 13 + 2 * w;
    float out[8];
    #pragma unroll
    for (int j = 0; j < 8; ++j) {
        int k = ko * 8 + j;
        int ic = k / 9, r = k % 9;
        int kh = r / 3, kw = r % 3;
        out[j] = hb[ic * 117 + kh * 13 + kw];
    }
    *(float4*)(B2 + (size_t)idx * 8) = *(const float4*)out;
    *(float4*)(B2 + (size_t)idx * 8 + 4) = *(const float4*)(out + 4);
}

// ---------------- pc GEMM (MFMA) + bias + squash -> u2[i][dh][b][4]  (d-half-major)
__global__ __launch_bounds__(256) void pc_gemm_kernel(
    const float* __restrict__ wpc, const float* __restrict__ bias,
    const float* __restrict__ B2, float* __restrict__ u2) {
    int wv = threadIdx.x >> 6;
    int l = threadIdx.x & 63;
    int q = l >> 4, r16 = l & 15;
    int c2t = blockIdx.y * 4 + wv;
    int n0 = blockIdx.x * 16;
    f32x4 acc = {0.f, 0.f, 0.f, 0.f};
    int c2a = c2t * 16 + r16;
    const float* ap0 = wpc + (size_t)c2a * 288 + q * 8;
    const float* bp0 = B2 + ((size_t)q * 3072 + n0 + r16) * 8;
    #pragma unroll
    for (int ks = 0; ks < 9; ++ks) {
        float av[8], bv[8];
        *(float4*)av = *(const float4*)(ap0 + ks * 32);
        *(float4*)(av + 4) = *(const float4*)(ap0 + ks * 32 + 4);
        *(float4*)bv = *(const float4*)(bp0 + (size_t)ks * 4 * 3072 * 8);
        *(float4*)(bv + 4) = *(const float4*)(bp0 + (size_t)ks * 4 * 3072 * 8 + 4);
        bfrag ahi, alo, bhi, blo;
        split8(av, ahi, alo);
        split8(bv, bhi, blo);
        acc = __builtin_amdgcn_mfma_f32_16x16x32_bf16(ahi, bhi, acc, 0, 0, 0);
        acc = __builtin_amdgcn_mfma_f32_16x16x32_bf16(ahi, blo, acc, 0, 0, 0);
        acc = __builtin_amdgcn_mfma_f32_16x16x32_bf16(alo, bhi, acc, 0, 0, 0);
    }
    int n = n0 + r16;
    int b = n / 24, s = n % 24;
    float vals[4], n2[4];
    #pragma unroll
    for (int r = 0; r < 4; ++r) {
        float xv = acc[r] + bias[c2t * 16 + q * 4 + r];
        vals[r] = xv;
        n2[r] = xv * xv;
    }
    #pragma unroll
    for (int r = 0; r < 4; ++r) {
        n2[r] += __shfl_xor(n2[r], 1, 64);
        n2[r] += __shfl_xor(n2[r], 2, 64);
        n2[r] += __shfl_xor(n2[r], 4, 64);
    }
    #pragma unroll
    for (int r = 0; r < 4; ++r) {
        int c2 = c2t * 16 + q * 4 + r;
        int cap = c2 * 3 + (s >> 3);
        int d = s & 7;
        float nr = sqrtf(n2[r]);
        u2[((size_t)(cap * 2 + (d >> 2)) * 128 + b) * 4 + (d & 3)]
            = vals[r] * nr / (1.f + n2[r]);
    }
}

// ---------------- s-pass (MFMA): per (o, it): s_part[it][b][o][k] = sum_{64 caps} c*(W@u)
template <bool UNIFORM>
__global__ __launch_bounds__(256) void spass_kernel(
    const float* __restrict__ W, const float* __restrict__ u2,
    const float* __restrict__ c_t, float* __restrict__ s_part) {
    int o = blockIdx.x;
    int it = blockIdx.y;
    int wv = threadIdx.x >> 6;
    int l = threadIdx.x & 63;
    int q = l >> 4, r16 = l & 15;
    int i0 = it * 64;
    f32x4 acc0 = {0.f, 0.f, 0.f, 0.f};
    f32x4 acc1 = {0.f, 0.f, 0.f, 0.f};
    for (int ch = 0; ch < 8; ++ch) {
        #pragma unroll
        for (int ks = 0; ks < 2; ++ks) {
            int cap = i0 + ch * 8 + ks * 4 + q;
            const float* wp = W + ((size_t)cap * 64 + o) * 128 + r16 * 8;
            float wv8[8];
            *(float4*)(wv8) = *(const float4*)wp;
            *(float4*)(wv8 + 4) = *(const float4*)(wp + 4);
            bfrag bhi, blo;
            split8(wv8, bhi, blo);
            #pragma unroll
            for (int m = 0; m < 2; ++m) {
                int b = wv * 32 + m * 16 + r16;
                float uv[8];
                *(float4*)(uv) = *(const float4*)(u2 + ((size_t)(cap * 2 + 0) * 128 + b) * 4);
                *(float4*)(uv + 4) = *(const float4*)(u2 + ((size_t)(cap * 2 + 1) * 128 + b) * 4);
                if (!UNIFORM) {
                    float c = c_t[((size_t)o * 768 + cap) * 128 + b];
                    #pragma unroll
                    for (int j = 0; j < 8; ++j) uv[j] *= c;
                }
                bfrag ahi, alo;
                split8(uv, ahi, alo);
                if (m == 0) {
                    acc0 = __builtin_amdgcn_mfma_f32_16x16x32_bf16(ahi, bhi, acc0, 0, 0, 0);
                    acc0 = __builtin_amdgcn_mfma_f32_16x16x32_bf16(ahi, blo, acc0, 0, 0, 0);
                    acc0 = __builtin_amdgcn_mfma_f32_16x16x32_bf16(alo, bhi, acc0, 0, 0, 0);
                } else {
                    acc1 = __builtin_amdgcn_mfma_f32_16x16x32_bf16(ahi, bhi, acc1, 0, 0, 0);
                    acc1 = __builtin_amdgcn_mfma_f32_16x16x32_bf16(ahi, blo, acc1, 0, 0, 0);
                    acc1 = __builtin_amdgcn_mfma_f32_16x16x32_bf16(alo, bhi, acc1, 0, 0, 0);
                }
            }
        }
    }
    #pragma unroll
    for (int reg = 0; reg < 4; ++reg) {
        int b0 = wv * 32 + q * 4 + reg;
        s_part[(((size_t)it * 128 + b0) * 64 + o) * 16 + r16] = acc0[reg];
        int b1 = b0 + 16;
        s_part[(((size_t)it * 128 + b1) * 64 + o) * 16 + r16] = acc1[reg];
    }
}

// ---------------- reduce partials + squash -> v ([b][o][k] for output, [o][b][k] for bpass)
template <bool TRANSPOSED>
__global__ __launch_bounds__(256) void squashv_kernel(
    const float* __restrict__ s_part, float* __restrict__ v, float scale) {
    int idx = blockIdx.x * 256 + threadIdx.x;  // b*1024 + o*16 + k
    float acc = 0.f;
    #pragma unroll
    for (int it = 0; it < 12; ++it) acc += s_part[(size_t)it * 131072 + idx];
    acc *= scale;
    float n2 = acc * acc;
    n2 += __shfl_xor(n2, 1, 64);
    n2 += __shfl_xor(n2, 2, 64);
    n2 += __shfl_xor(n2, 4, 64);
    n2 += __shfl_xor(n2, 8, 64);
    float n = sqrtf(n2);
    float val = acc * n / (1.f + n2);
    if (TRANSPOSED) {
        int k = idx & 15, o = (idx >> 4) & 63, b = idx >> 10;
        v[((size_t)o * 128 + b) * 16 + k] = val;
    } else {
        v[idx] = val;
    }
}

// ---------------- b-pass (32x32x16 MFMA, K=16 exact), W staged via LDS transposed.
// Per (o, it of 64 caps): Wv[(cap,d), b] = sum_k W[cap,o,k,d] v[b,o,k];
// blog[o,cap,b] (+)= sum_d u[b,cap,d] Wv[(cap,d),b]
// LDS wl[cl][d][k]: pitches 164/20 dwords -> ds_read_b128 conflict-free
// (4-dword group = (g + 5d + 2kh) mod 8, uniform 8 lanes/group).
// A-frag lane l (row r=l&31): cap=cl0+(r>>3), d=r&7, k=kh*8+j -> wl row, 2x b128.
// B-frag lane l: col b=nt*32+r; k=kh*8+j -> v_t[o][b][kh*8..+8] coalesced.
// C/D [m74/m101]: col=l&31=b, row=(reg&3)+8*(reg>>2)+4*kh -> cap_sub=reg>>2, d=(reg&3)+4*kh.
template <bool ACCUM>
__global__ __launch_bounds__(256, 3) void bpass_kernel(
    const float* __restrict__ W, const float* __restrict__ u2,
    const float* __restrict__ v_t, float* __restrict__ blog) {
    int o = blockIdx.x, it = blockIdx.y;   // it: 0..11 (64 caps)
    int tid = threadIdx.x;
    int wv = tid >> 6;
    int l = tid & 63;
    int r = l & 31;
    int kh = l >> 5;
    int capB = it * 64;
    __shared__ float wl[64 * 164];
    // stage W tile (64 caps x 128) coalesced, store transposed [cl][d][k]
    #pragma unroll
    for (int itr = 0; itr < 8; ++itr) {
        int F = tid + 256 * itr;           // 0..2047 float4s
        int cap = F >> 5, slot = F & 31;
        int k = slot >> 1, dh = slot & 1;
        float4 t4 = *(const float4*)(W + ((size_t)(capB + cap) * 64 + o) * 128 + k * 8 + dh * 4);
        float* dst = wl + cap * 164 + (dh * 4) * 20 + k;
        dst[0] = t4.x; dst[20] = t4.y; dst[40] = t4.z; dst[60] = t4.w;
    }
    // hoist B-frags (v) — coalesced from v_t[o][b][16]
    bfrag vhi[4], vlo[4];
    #pragma unroll
    for (int nt = 0; nt < 4; ++nt) {
        const float* vp = v_t + ((size_t)o * 128 + nt * 32 + r) * 16 + kh * 8;
        float vv8[8];
        *(float4*)(vv8) = *(const float4*)vp;
        *(float4*)(vv8 + 4) = *(const float4*)(vp + 4);
        split8(vv8, vhi[nt], vlo[nt]);
    }
    __syncthreads();
    #pragma unroll
    for (int mt = 0; mt < 4; ++mt) {
        int cl = wv * 16 + mt * 4 + (r >> 3);
        const float* ap = wl + cl * 164 + (r & 7) * 20 + kh * 8;
        float a8[8];
        *(float4*)(a8) = *(const float4*)ap;
        *(float4*)(a8 + 4) = *(const float4*)(ap + 4);
        bfrag ahi, alo;
        split8(a8, ahi, alo);
        int capg = capB + wv * 16 + mt * 4;
        #pragma unroll
        for (int nt = 0; nt < 4; ++nt) {
            f32x16 acc;
            #pragma unroll
            for (int z = 0; z < 16; ++z) acc[z] = 0.f;
            acc = __builtin_amdgcn_mfma_f32_32x32x16_bf16(ahi, vhi[nt], acc, 0, 0, 0);
            acc = __builtin_amdgcn_mfma_f32_32x32x16_bf16(ahi, vlo[nt], acc, 0, 0, 0);
            acc = __builtin_amdgcn_mfma_f32_32x32x16_bf16(alo, vhi[nt], acc, 0, 0, 0);
            int b = nt * 32 + r;
            #pragma unroll
            for (int g = 0; g < 4; ++g) {
                int cap = capg + g;
                float4 u4 = *(const float4*)(u2 + ((size_t)(cap * 2 + kh) * 128 + b) * 4);
                float part = u4.x * acc[g * 4 + 0] + u4.y * acc[g * 4 + 1]
                           + u4.z * acc[g * 4 + 2] + u4.w * acc[g * 4 + 3];
                float full = part + __shfl_xor(part, 32, 64);
                if (!kh) {
                    size_t bi = ((size_t)o * 768 + cap) * 128 + b;
                    blog[bi] = (ACCUM ? blog[bi] : 0.f) + full;
                }
            }
        }
    }
}

// ---------------- softmax over o: c_t[o][i][b] = softmax_o(blog[o][i][b])
__global__ __launch_bounds__(128) void softmax_kernel(
    const float* __restrict__ blog, float* __restrict__ c_t) {
    int i = blockIdx.x;
    int b = threadIdx.x;
    const float* src = blog + (size_t)i * 128 + b;
    float r[64];
    float m = -1e30f;
    #pragma unroll
    for (int o = 0; o < 64; ++o) {
        r[o] = src[(size_t)o * 98304];
        m = fmaxf(m, r[o]);
    }
    float sum = 0.f;
    #pragma unroll
    for (int o = 0; o < 64; ++o) {
        r[o] = __expf(r[o] - m);
        sum += r[o];
    }
    float inv = 1.f / sum;
    float* dst = c_t + (size_t)i * 128 + b;
    #pragma unroll
    for (int o = 0; o < 64; ++o) dst[(size_t)o * 98304] = r[o] * inv;
}

extern "C" void kernel_launch(void* const* d_in, const int* in_sizes, int n_in,
                              void* d_out, int out_size, void* d_ws, size_t ws_size,
                              hipStream_t stream) {
    const float* x  = (const float*)d_in[0];
    const float* w1 = (const float*)d_in[1];
    const float* b1 = (const float*)d_in[2];
    const float* wp = (const float*)d_in[3];
    const float* bp = (const float*)d_in[4];
    const float* W  = (const float*)d_in[5];
    float* out = (float*)d_out;
    float* ws = (float*)d_ws;

    float* u2     = ws;                  // 786432
    float* c_t    = ws + 786432;         // 6291456 (B2 im2col reuses this region pre-routing)
    float* blog   = ws + 7077888;        // 6291456
    float* v      = ws + 13369344;       // 131072
    float* h1     = ws + 13500416;       // 479232 (region reused by s_part)
    float* s_part = ws + 13500416;       // 1572864
    float* B2     = c_t;                 // 884736 floats, dead before softmax writes c_t

    conv1_kernel<<<1872, 256, 0, stream>>>(x, w1, b1, h1);
    im2col_kernel<<<432, 256, 0, stream>>>(h1, B2);
    pc_gemm_kernel<<<dim3(192, 4), 256, 0, stream>>>(wp, bp, B2, u2);

    // iteration 0: c uniform (1/64 folded into squash scale)
    spass_kernel<true><<<dim3(64, 12), 256, 0, stream>>>(W, u2, nullptr, s_part);
    squashv_kernel<true><<<512, 256, 0, stream>>>(s_part, v, 1.f / 64.f);
    bpass_kernel<false><<<dim3(64, 12), 256, 0, stream>>>(W, u2, v, blog);

    // iteration 1
    softmax_kernel<<<768, 128, 0, stream>>>(blog, c_t);
    spass_kernel<false><<<dim3(64, 12), 256, 0, stream>>>(W, u2, c_t, s_part);
    squashv_kernel<true><<<512, 256, 0, stream>>>(s_part, v, 1.f);
    bpass_kernel<true><<<dim3(64, 12), 256, 0, stream>>>(W, u2, v, blog);

    // final
    softmax_kernel<<<768, 128, 0, stream>>>(blog, c_t);
    spass_kernel<false><<<dim3(64, 12), 256, 0, stream>>>(W, u2, c_t, s_part);
    squashv_kernel<false><<<512, 256, 0, stream>>>(s_part, out, 1.f);
}

// Round 7
// 204.550 us; speedup vs baseline: 1.0825x; 1.0825x over previous
//
#include <hip/hip_runtime.h>
#include <math.h>

#define BATCH 128
#define NCI 768
#define NCO 64
#define DIN 8
#define DOUT 16

typedef __attribute__((ext_vector_type(8))) short bfrag;    // 8 bf16 = 4 VGPR
typedef __attribute__((ext_vector_type(4))) float f32x4;    // 16x16 accumulator
typedef __attribute__((ext_vector_type(16))) float f32x16;  // 32x32 accumulator

// split 8 f32 into bf16 hi (truncation) + bf16 lo (truncation of remainder).
// x = hi + lo with |err| ~ 2^-16 |x|; 3-term MFMA (hh + hl + lh) ~ fp32 precision.
__device__ __forceinline__ void split8(const float* x, bfrag& hi, bfrag& lo) {
    #pragma unroll
    for (int j = 0; j < 8; ++j) {
        unsigned xb = __float_as_uint(x[j]);
        unsigned hb = xb & 0xffff0000u;
        float lf = x[j] - __uint_as_float(hb);
        hi[j] = (short)(xb >> 16);
        lo[j] = (short)(__float_as_uint(lf) >> 16);
    }
}

// ---------------- conv1: x(128,3,32,42) w(32,3,6,6) stride 3 -> h1(128,32,9,13), relu
__global__ __launch_bounds__(256) void conv1_kernel(
    const float* __restrict__ x, const float* __restrict__ w,
    const float* __restrict__ bias, float* __restrict__ h1) {
    __shared__ float wl[32 * 3 * 36];
    for (int i = threadIdx.x; i < 3456; i += 256) wl[i] = w[i];
    __syncthreads();
    int idx = blockIdx.x * 256 + threadIdx.x;
    const int total = BATCH * 32 * 9 * 13;
    if (idx >= total) return;
    int ow = idx % 13; int t = idx / 13;
    int oh = t % 9; t /= 9;
    int oc = t % 32; int b = t / 32;
    float acc = bias[oc];
    const float* xb = x + (size_t)b * 3 * 32 * 42;
    #pragma unroll
    for (int ic = 0; ic < 3; ++ic) {
        const float* xc = xb + ic * 32 * 42 + (oh * 3) * 42 + ow * 3;
        const float* wc = wl + (oc * 3 + ic) * 36;
        #pragma unroll
        for (int kh = 0; kh < 6; ++kh)
            #pragma unroll
            for (int kw = 0; kw < 6; ++kw)
                acc += xc[kh * 42 + kw] * wc[kh * 6 + kw];
    }
    h1[idx] = fmaxf(acc, 0.f);
}

// ---------------- im2col for primary-caps conv: B2[ko][n][j], ko=K-octet (36), n=(b,s) (3072)
__global__ __launch_bounds__(256) void im2col_kernel(
    const float* __restrict__ h1, float* __restrict__ B2) {
    int idx = blockIdx.x * 256 + threadIdx.x;
    if (idx >= 36 * 3072) return;
    int n = idx % 3072, ko = idx / 3072;
    int b = n / 24, s = n % 24, h = s / 6, w = s % 6;
    const float* hb = h1 + (size_t)b * 3744 + (2 * h) * 13 + 2 * w;
    float out[8];
    #pragma unroll
    for (int j = 0; j < 8; ++j) {
        int k = ko * 8 + j;
        int ic = k / 9, r = k % 9;
        int kh = r / 3, kw = r % 3;
        out[j] = hb[ic * 117 + kh * 13 + kw];
    }
    *(float4*)(B2 + (size_t)idx * 8) = *(const float4*)out;
    *(float4*)(B2 + (size_t)idx * 8 + 4) = *(const float4*)(out + 4);
}

// ---------------- pc GEMM (MFMA) + bias + squash -> u2[i][dh][b][4]  (d-half-major)
__global__ __launch_bounds__(256) void pc_gemm_kernel(
    const float* __restrict__ wpc, const float* __restrict__ bias,
    const float* __restrict__ B2, float* __restrict__ u2) {
    int wv = threadIdx.x >> 6;
    int l = threadIdx.x & 63;
    int q = l >> 4, r16 = l & 15;
    int c2t = blockIdx.y * 4 + wv;
    int n0 = blockIdx.x * 16;
    f32x4 acc = {0.f, 0.f, 0.f, 0.f};
    int c2a = c2t * 16 + r16;
    const float* ap0 = wpc + (size_t)c2a * 288 + q * 8;
    const float* bp0 = B2 + ((size_t)q * 3072 + n0 + r16) * 8;
    #pragma unroll
    for (int ks = 0; ks < 9; ++ks) {
        float av[8], bv[8];
        *(float4*)av = *(const float4*)(ap0 + ks * 32);
        *(float4*)(av + 4) = *(const float4*)(ap0 + ks * 32 + 4);
        *(float4*)bv = *(const float4*)(bp0 + (size_t)ks * 4 * 3072 * 8);
        *(float4*)(bv + 4) = *(const float4*)(bp0 + (size_t)ks * 4 * 3072 * 8 + 4);
        bfrag ahi, alo, bhi, blo;
        split8(av, ahi, alo);
        split8(bv, bhi, blo);
        acc = __builtin_amdgcn_mfma_f32_16x16x32_bf16(ahi, bhi, acc, 0, 0, 0);
        acc = __builtin_amdgcn_mfma_f32_16x16x32_bf16(ahi, blo, acc, 0, 0, 0);
        acc = __builtin_amdgcn_mfma_f32_16x16x32_bf16(alo, bhi, acc, 0, 0, 0);
    }
    int n = n0 + r16;
    int b = n / 24, s = n % 24;
    float vals[4], n2[4];
    #pragma unroll
    for (int r = 0; r < 4; ++r) {
        float xv = acc[r] + bias[c2t * 16 + q * 4 + r];
        vals[r] = xv;
        n2[r] = xv * xv;
    }
    #pragma unroll
    for (int r = 0; r < 4; ++r) {
        n2[r] += __shfl_xor(n2[r], 1, 64);
        n2[r] += __shfl_xor(n2[r], 2, 64);
        n2[r] += __shfl_xor(n2[r], 4, 64);
    }
    #pragma unroll
    for (int r = 0; r < 4; ++r) {
        int c2 = c2t * 16 + q * 4 + r;
        int cap = c2 * 3 + (s >> 3);
        int d = s & 7;
        float nr = sqrtf(n2[r]);
        u2[((size_t)(cap * 2 + (d >> 2)) * 128 + b) * 4 + (d & 3)]
            = vals[r] * nr / (1.f + n2[r]);
    }
}

// ---------------- mz: per (i,b) softmax stats over o: m = max, z = 1/sum(exp(.-m))
__global__ __launch_bounds__(128) void mz_kernel(
    const float* __restrict__ blog, float* __restrict__ m_, float* __restrict__ z_) {
    int i = blockIdx.x;
    int b = threadIdx.x;
    const float* src = blog + (size_t)i * 128 + b;
    float r[64];
    float m = -1e30f;
    #pragma unroll
    for (int o = 0; o < 64; ++o) {
        r[o] = src[(size_t)o * 98304];
        m = fmaxf(m, r[o]);
    }
    float sum = 0.f;
    #pragma unroll
    for (int o = 0; o < 64; ++o) sum += __expf(r[o] - m);
    m_[i * 128 + b] = m;
    z_[i * 128 + b] = 1.f / sum;
}

// ---------------- s-pass (MFMA): per (o, it of 32 caps): s_part[it][b][o][k]
// c computed inline: c = exp(blog[o,cap,b] - m[cap,b]) * z[cap,b]
template <bool UNIFORM>
__global__ __launch_bounds__(256) void spass_kernel(
    const float* __restrict__ W, const float* __restrict__ u2,
    const float* __restrict__ blog, const float* __restrict__ m_,
    const float* __restrict__ z_, float* __restrict__ s_part) {
    int o = blockIdx.x;
    int it = blockIdx.y;       // 0..23 (32 caps)
    int wv = threadIdx.x >> 6;
    int l = threadIdx.x & 63;
    int q = l >> 4, r16 = l & 15;
    int i0 = it * 32;
    f32x4 acc0 = {0.f, 0.f, 0.f, 0.f};
    f32x4 acc1 = {0.f, 0.f, 0.f, 0.f};
    for (int ch = 0; ch < 4; ++ch) {
        #pragma unroll
        for (int ks = 0; ks < 2; ++ks) {
            int cap = i0 + ch * 8 + ks * 4 + q;
            const float* wp = W + ((size_t)cap * 64 + o) * 128 + r16 * 8;
            float wv8[8];
            *(float4*)(wv8) = *(const float4*)wp;
            *(float4*)(wv8 + 4) = *(const float4*)(wp + 4);
            bfrag bhi, blo;
            split8(wv8, bhi, blo);
            #pragma unroll
            for (int m = 0; m < 2; ++m) {
                int b = wv * 32 + m * 16 + r16;
                float uv[8];
                *(float4*)(uv) = *(const float4*)(u2 + ((size_t)(cap * 2 + 0) * 128 + b) * 4);
                *(float4*)(uv + 4) = *(const float4*)(u2 + ((size_t)(cap * 2 + 1) * 128 + b) * 4);
                if (!UNIFORM) {
                    float c = __expf(blog[((size_t)o * 768 + cap) * 128 + b]
                                     - m_[cap * 128 + b]) * z_[cap * 128 + b];
                    #pragma unroll
                    for (int j = 0; j < 8; ++j) uv[j] *= c;
                }
                bfrag ahi, alo;
                split8(uv, ahi, alo);
                if (m == 0) {
                    acc0 = __builtin_amdgcn_mfma_f32_16x16x32_bf16(ahi, bhi, acc0, 0, 0, 0);
                    acc0 = __builtin_amdgcn_mfma_f32_16x16x32_bf16(ahi, blo, acc0, 0, 0, 0);
                    acc0 = __builtin_amdgcn_mfma_f32_16x16x32_bf16(alo, bhi, acc0, 0, 0, 0);
                } else {
                    acc1 = __builtin_amdgcn_mfma_f32_16x16x32_bf16(ahi, bhi, acc1, 0, 0, 0);
                    acc1 = __builtin_amdgcn_mfma_f32_16x16x32_bf16(ahi, blo, acc1, 0, 0, 0);
                    acc1 = __builtin_amdgcn_mfma_f32_16x16x32_bf16(alo, bhi, acc1, 0, 0, 0);
                }
            }
        }
    }
    #pragma unroll
    for (int reg = 0; reg < 4; ++reg) {
        int b0 = wv * 32 + q * 4 + reg;
        s_part[(((size_t)it * 128 + b0) * 64 + o) * 16 + r16] = acc0[reg];
        int b1 = b0 + 16;
        s_part[(((size_t)it * 128 + b1) * 64 + o) * 16 + r16] = acc1[reg];
    }
}

// ---------------- reduce partials + squash -> v ([b][o][k] for output, [o][b][k] for bpass)
template <bool TRANSPOSED>
__global__ __launch_bounds__(256) void squashv_kernel(
    const float* __restrict__ s_part, float* __restrict__ v, float scale) {
    int idx = blockIdx.x * 256 + threadIdx.x;  // b*1024 + o*16 + k
    float acc = 0.f;
    #pragma unroll
    for (int it = 0; it < 24; ++it) acc += s_part[(size_t)it * 131072 + idx];
    acc *= scale;
    float n2 = acc * acc;
    n2 += __shfl_xor(n2, 1, 64);
    n2 += __shfl_xor(n2, 2, 64);
    n2 += __shfl_xor(n2, 4, 64);
    n2 += __shfl_xor(n2, 8, 64);
    float n = sqrtf(n2);
    float val = acc * n / (1.f + n2);
    if (TRANSPOSED) {
        int k = idx & 15, o = (idx >> 4) & 63, b = idx >> 10;
        v[((size_t)o * 128 + b) * 16 + k] = val;
    } else {
        v[idx] = val;
    }
}

// ---------------- b-pass (32x32x16 MFMA, K=16 exact), W staged via LDS transposed.
// 32-cap tiles for occupancy. See R5/R6 comments for fragment derivations.
template <bool ACCUM>
__global__ __launch_bounds__(256, 4) void bpass_kernel(
    const float* __restrict__ W, const float* __restrict__ u2,
    const float* __restrict__ v_t, float* __restrict__ blog) {
    int o = blockIdx.x, it = blockIdx.y;   // it: 0..23 (32 caps)
    int tid = threadIdx.x;
    int wv = tid >> 6;
    int l = tid & 63;
    int r = l & 31;
    int kh = l >> 5;
    int capB = it * 32;
    __shared__ float wl[32 * 164];
    // stage W tile (32 caps x 128) coalesced, store transposed [cl][d][k]
    #pragma unroll
    for (int itr = 0; itr < 4; ++itr) {
        int F = tid + 256 * itr;           // 0..1023 float4s
        int cap = F >> 5, slot = F & 31;
        int k = slot >> 1, dh = slot & 1;
        float4 t4 = *(const float4*)(W + ((size_t)(capB + cap) * 64 + o) * 128 + k * 8 + dh * 4);
        float* dst = wl + cap * 164 + (dh * 4) * 20 + k;
        dst[0] = t4.x; dst[20] = t4.y; dst[40] = t4.z; dst[60] = t4.w;
    }
    // hoist B-frags (v) — coalesced from v_t[o][b][16]
    bfrag vhi[4], vlo[4];
    #pragma unroll
    for (int nt = 0; nt < 4; ++nt) {
        const float* vp = v_t + ((size_t)o * 128 + nt * 32 + r) * 16 + kh * 8;
        float vv8[8];
        *(float4*)(vv8) = *(const float4*)vp;
        *(float4*)(vv8 + 4) = *(const float4*)(vp + 4);
        split8(vv8, vhi[nt], vlo[nt]);
    }
    __syncthreads();
    #pragma unroll
    for (int mt = 0; mt < 2; ++mt) {
        int cl = wv * 8 + mt * 4 + (r >> 3);
        const float* ap = wl + cl * 164 + (r & 7) * 20 + kh * 8;
        float a8[8];
        *(float4*)(a8) = *(const float4*)ap;
        *(float4*)(a8 + 4) = *(const float4*)(ap + 4);
        bfrag ahi, alo;
        split8(a8, ahi, alo);
        int capg = capB + wv * 8 + mt * 4;
        #pragma unroll
        for (int nt = 0; nt < 4; ++nt) {
            f32x16 acc;
            #pragma unroll
            for (int z = 0; z < 16; ++z) acc[z] = 0.f;
            acc = __builtin_amdgcn_mfma_f32_32x32x16_bf16(ahi, vhi[nt], acc, 0, 0, 0);
            acc = __builtin_amdgcn_mfma_f32_32x32x16_bf16(ahi, vlo[nt], acc, 0, 0, 0);
            acc = __builtin_amdgcn_mfma_f32_32x32x16_bf16(alo, vhi[nt], acc, 0, 0, 0);
            int b = nt * 32 + r;
            #pragma unroll
            for (int g = 0; g < 4; ++g) {
                int cap = capg + g;
                float4 u4 = *(const float4*)(u2 + ((size_t)(cap * 2 + kh) * 128 + b) * 4);
                float part = u4.x * acc[g * 4 + 0] + u4.y * acc[g * 4 + 1]
                           + u4.z * acc[g * 4 + 2] + u4.w * acc[g * 4 + 3];
                float full = part + __shfl_xor(part, 32, 64);
                if (!kh) {
                    size_t bi = ((size_t)o * 768 + cap) * 128 + b;
                    blog[bi] = (ACCUM ? blog[bi] : 0.f) + full;
                }
            }
        }
    }
}

extern "C" void kernel_launch(void* const* d_in, const int* in_sizes, int n_in,
                              void* d_out, int out_size, void* d_ws, size_t ws_size,
                              hipStream_t stream) {
    const float* x  = (const float*)d_in[0];
    const float* w1 = (const float*)d_in[1];
    const float* b1 = (const float*)d_in[2];
    const float* wp = (const float*)d_in[3];
    const float* bp = (const float*)d_in[4];
    const float* W  = (const float*)d_in[5];
    float* out = (float*)d_out;
    float* ws = (float*)d_ws;

    float* u2     = ws;                  // 786432
    float* blog   = ws + 786432;         // 6291456
    float* m_     = ws + 7077888;        // 98304
    float* z_     = ws + 7176192;        // 98304
    float* v      = ws + 7274496;        // 131072
    float* s_part = ws + 7405568;        // 3145728 (ends at 10551296 floats = 42.2 MB)
    float* B2     = s_part;              // 884736, dead before spass writes s_part
    float* h1     = s_part + 884736;     // 479232, dead before spass

    conv1_kernel<<<1872, 256, 0, stream>>>(x, w1, b1, h1);
    im2col_kernel<<<432, 256, 0, stream>>>(h1, B2);
    pc_gemm_kernel<<<dim3(192, 4), 256, 0, stream>>>(wp, bp, B2, u2);

    // iteration 0: c uniform (1/64 folded into squash scale)
    spass_kernel<true><<<dim3(64, 24), 256, 0, stream>>>(W, u2, nullptr, nullptr, nullptr, s_part);
    squashv_kernel<true><<<512, 256, 0, stream>>>(s_part, v, 1.f / 64.f);
    bpass_kernel<false><<<dim3(64, 24), 256, 0, stream>>>(W, u2, v, blog);

    // iteration 1 (softmax fused into spass via mz stats)
    mz_kernel<<<768, 128, 0, stream>>>(blog, m_, z_);
    spass_kernel<false><<<dim3(64, 24), 256, 0, stream>>>(W, u2, blog, m_, z_, s_part);
    squashv_kernel<true><<<512, 256, 0, stream>>>(s_part, v, 1.f);
    bpass_kernel<true><<<dim3(64, 24), 256, 0, stream>>>(W, u2, v, blog);

    // final
    mz_kernel<<<768, 128, 0, stream>>>(blog, m_, z_);
    spass_kernel<false><<<dim3(64, 24), 256, 0, stream>>>(W, u2, blog, m_, z_, s_part);
    squashv_kernel<false><<<512, 256, 0, stream>>>(s_part, out, 1.f);
}

// Round 8
// 172.027 us; speedup vs baseline: 1.2872x; 1.1891x over previous
//
#include <hip/hip_runtime.h>
#include <math.h>

#define BATCH 128
#define NCI 768
#define NCO 64
#define DIN 8
#define DOUT 16

typedef __attribute__((ext_vector_type(8))) short bfrag;    // 8 bf16 = 4 VGPR
typedef __attribute__((ext_vector_type(4))) float f32x4;    // 16x16 accumulator
typedef __attribute__((ext_vector_type(16))) float f32x16;  // 32x32 accumulator

// split 8 f32 into bf16 hi (truncation) + bf16 lo (truncation of remainder).
// x = hi + lo with |err| ~ 2^-16 |x|; 3-term MFMA (hh + hl + lh) ~ fp32 precision.
__device__ __forceinline__ void split8(const float* x, bfrag& hi, bfrag& lo) {
    #pragma unroll
    for (int j = 0; j < 8; ++j) {
        unsigned xb = __float_as_uint(x[j]);
        unsigned hb = xb & 0xffff0000u;
        float lf = x[j] - __uint_as_float(hb);
        hi[j] = (short)(xb >> 16);
        lo[j] = (short)(__float_as_uint(lf) >> 16);
    }
}

// ---------------- conv1: x(128,3,32,42) w(32,3,6,6) stride 3 -> h1(128,32,9,13), relu
__global__ __launch_bounds__(256) void conv1_kernel(
    const float* __restrict__ x, const float* __restrict__ w,
    const float* __restrict__ bias, float* __restrict__ h1) {
    __shared__ float wl[32 * 3 * 36];
    for (int i = threadIdx.x; i < 3456; i += 256) wl[i] = w[i];
    __syncthreads();
    int idx = blockIdx.x * 256 + threadIdx.x;
    const int total = BATCH * 32 * 9 * 13;
    if (idx >= total) return;
    int ow = idx % 13; int t = idx / 13;
    int oh = t % 9; t /= 9;
    int oc = t % 32; int b = t / 32;
    float acc = bias[oc];
    const float* xb = x + (size_t)b * 3 * 32 * 42;
    #pragma unroll
    for (int ic = 0; ic < 3; ++ic) {
        const float* xc = xb + ic * 32 * 42 + (oh * 3) * 42 + ow * 3;
        const float* wc = wl + (oc * 3 + ic) * 36;
        #pragma unroll
        for (int kh = 0; kh < 6; ++kh)
            #pragma unroll
            for (int kw = 0; kw < 6; ++kw)
                acc += xc[kh * 42 + kw] * wc[kh * 6 + kw];
    }
    h1[idx] = fmaxf(acc, 0.f);
}

// ---------------- im2col for primary-caps conv: B2[ko][n][j], ko=K-octet (36), n=(b,s) (3072)
__global__ __launch_bounds__(256) void im2col_kernel(
    const float* __restrict__ h1, float* __restrict__ B2) {
    int idx = blockIdx.x * 256 + threadIdx.x;
    if (idx >= 36 * 3072) return;
    int n = idx % 3072, ko = idx / 3072;
    int b = n / 24, s = n % 24, h = s / 6, w = s % 6;
    const float* hb = h1 + (size_t)b * 3744 + (2 * h) * 13 + 2 * w;
    float out[8];
    #pragma unroll
    for (int j = 0; j < 8; ++j) {
        int k = ko * 8 + j;
        int ic = k / 9, r = k % 9;
        int kh = r / 3, kw = r % 3;
        out[j] = hb[ic * 117 + kh * 13 + kw];
    }
    *(float4*)(B2 + (size_t)idx * 8) = *(const float4*)out;
    *(float4*)(B2 + (size_t)idx * 8 + 4) = *(const float4*)(out + 4);
}

// ---------------- pc GEMM (MFMA) + bias + squash -> u2[i][dh][b][4]  (d-half-major)
__global__ __launch_bounds__(256) void pc_gemm_kernel(
    const float* __restrict__ wpc, const float* __restrict__ bias,
    const float* __restrict__ B2, float* __restrict__ u2) {
    int wv = threadIdx.x >> 6;
    int l = threadIdx.x & 63;
    int q = l >> 4, r16 = l & 15;
    int c2t = blockIdx.y * 4 + wv;
    int n0 = blockIdx.x * 16;
    f32x4 acc = {0.f, 0.f, 0.f, 0.f};
    int c2a = c2t * 16 + r16;
    const float* ap0 = wpc + (size_t)c2a * 288 + q * 8;
    const float* bp0 = B2 + ((size_t)q * 3072 + n0 + r16) * 8;
    #pragma unroll
    for (int ks = 0; ks < 9; ++ks) {
        float av[8], bv[8];
        *(float4*)av = *(const float4*)(ap0 + ks * 32);
        *(float4*)(av + 4) = *(const float4*)(ap0 + ks * 32 + 4);
        *(float4*)bv = *(const float4*)(bp0 + (size_t)ks * 4 * 3072 * 8);
        *(float4*)(bv + 4) = *(const float4*)(bp0 + (size_t)ks * 4 * 3072 * 8 + 4);
        bfrag ahi, alo, bhi, blo;
        split8(av, ahi, alo);
        split8(bv, bhi, blo);
        acc = __builtin_amdgcn_mfma_f32_16x16x32_bf16(ahi, bhi, acc, 0, 0, 0);
        acc = __builtin_amdgcn_mfma_f32_16x16x32_bf16(ahi, blo, acc, 0, 0, 0);
        acc = __builtin_amdgcn_mfma_f32_16x16x32_bf16(alo, bhi, acc, 0, 0, 0);
    }
    int n = n0 + r16;
    int b = n / 24, s = n % 24;
    float vals[4], n2[4];
    #pragma unroll
    for (int r = 0; r < 4; ++r) {
        float xv = acc[r] + bias[c2t * 16 + q * 4 + r];
        vals[r] = xv;
        n2[r] = xv * xv;
    }
    #pragma unroll
    for (int r = 0; r < 4; ++r) {
        n2[r] += __shfl_xor(n2[r], 1, 64);
        n2[r] += __shfl_xor(n2[r], 2, 64);
        n2[r] += __shfl_xor(n2[r], 4, 64);
    }
    #pragma unroll
    for (int r = 0; r < 4; ++r) {
        int c2 = c2t * 16 + q * 4 + r;
        int cap = c2 * 3 + (s >> 3);
        int d = s & 7;
        float nr = sqrtf(n2[r]);
        u2[((size_t)(cap * 2 + (d >> 2)) * 128 + b) * 4 + (d & 3)]
            = vals[r] * nr / (1.f + n2[r]);
    }
}

// ---------------- mz: per (i,b) softmax stats over o: m = max, z = 1/sum(exp(.-m))
__global__ __launch_bounds__(128) void mz_kernel(
    const float* __restrict__ blog, float* __restrict__ m_, float* __restrict__ z_) {
    int i = blockIdx.x;
    int b = threadIdx.x;
    const float* src = blog + (size_t)i * 128 + b;
    float r[64];
    float m = -1e30f;
    #pragma unroll
    for (int o = 0; o < 64; ++o) {
        r[o] = src[(size_t)o * 98304];
        m = fmaxf(m, r[o]);
    }
    float sum = 0.f;
    #pragma unroll
    for (int o = 0; o < 64; ++o) sum += __expf(r[o] - m);
    m_[i * 128 + b] = m;
    z_[i * 128 + b] = 1.f / sum;
}

// ---------------- s-pass (MFMA): per (o, it of 32 caps): s_part[it][b][o][k]
// c computed inline: c = exp(blog[o,cap,b] - m[cap,b]) * z[cap,b]
// All loads of one (ch,ks) step issued together before compute (single latency).
template <bool UNIFORM>
__global__ __launch_bounds__(256) void spass_kernel(
    const float* __restrict__ W, const float* __restrict__ u2,
    const float* __restrict__ blog, const float* __restrict__ m_,
    const float* __restrict__ z_, float* __restrict__ s_part) {
    int o = blockIdx.x;
    int it = blockIdx.y;       // 0..23 (32 caps)
    int wv = threadIdx.x >> 6;
    int l = threadIdx.x & 63;
    int q = l >> 4, r16 = l & 15;
    int i0 = it * 32;
    f32x4 acc0 = {0.f, 0.f, 0.f, 0.f};
    f32x4 acc1 = {0.f, 0.f, 0.f, 0.f};
    for (int ch = 0; ch < 4; ++ch) {
        #pragma unroll
        for (int ks = 0; ks < 2; ++ks) {
            int cap = i0 + ch * 8 + ks * 4 + q;
            // ---- issue ALL loads first (independent)
            const float* wp = W + ((size_t)cap * 64 + o) * 128 + r16 * 8;
            float4 w0 = *(const float4*)wp;
            float4 w1 = *(const float4*)(wp + 4);
            float4 ua[2][2];
            float bl[2], mv[2], zv[2];
            #pragma unroll
            for (int m = 0; m < 2; ++m) {
                int b = wv * 32 + m * 16 + r16;
                ua[m][0] = *(const float4*)(u2 + ((size_t)(cap * 2 + 0) * 128 + b) * 4);
                ua[m][1] = *(const float4*)(u2 + ((size_t)(cap * 2 + 1) * 128 + b) * 4);
                if (!UNIFORM) {
                    bl[m] = blog[((size_t)o * 768 + cap) * 128 + b];
                    mv[m] = m_[cap * 128 + b];
                    zv[m] = z_[cap * 128 + b];
                }
            }
            // ---- compute
            float wv8[8];
            *(float4*)(wv8) = w0;
            *(float4*)(wv8 + 4) = w1;
            bfrag bhi, blo;
            split8(wv8, bhi, blo);
            #pragma unroll
            for (int m = 0; m < 2; ++m) {
                float uv[8];
                *(float4*)(uv) = ua[m][0];
                *(float4*)(uv + 4) = ua[m][1];
                if (!UNIFORM) {
                    float c = __expf(bl[m] - mv[m]) * zv[m];
                    #pragma unroll
                    for (int j = 0; j < 8; ++j) uv[j] *= c;
                }
                bfrag ahi, alo;
                split8(uv, ahi, alo);
                if (m == 0) {
                    acc0 = __builtin_amdgcn_mfma_f32_16x16x32_bf16(ahi, bhi, acc0, 0, 0, 0);
                    acc0 = __builtin_amdgcn_mfma_f32_16x16x32_bf16(ahi, blo, acc0, 0, 0, 0);
                    acc0 = __builtin_amdgcn_mfma_f32_16x16x32_bf16(alo, bhi, acc0, 0, 0, 0);
                } else {
                    acc1 = __builtin_amdgcn_mfma_f32_16x16x32_bf16(ahi, bhi, acc1, 0, 0, 0);
                    acc1 = __builtin_amdgcn_mfma_f32_16x16x32_bf16(ahi, blo, acc1, 0, 0, 0);
                    acc1 = __builtin_amdgcn_mfma_f32_16x16x32_bf16(alo, bhi, acc1, 0, 0, 0);
                }
            }
        }
    }
    #pragma unroll
    for (int reg = 0; reg < 4; ++reg) {
        int b0 = wv * 32 + q * 4 + reg;
        s_part[(((size_t)it * 128 + b0) * 64 + o) * 16 + r16] = acc0[reg];
        int b1 = b0 + 16;
        s_part[(((size_t)it * 128 + b1) * 64 + o) * 16 + r16] = acc1[reg];
    }
}

// ---------------- reduce partials + squash -> v ([b][o][k] for output, [o][b][k] for bpass)
template <bool TRANSPOSED>
__global__ __launch_bounds__(256) void squashv_kernel(
    const float* __restrict__ s_part, float* __restrict__ v, float scale) {
    int idx = blockIdx.x * 256 + threadIdx.x;  // b*1024 + o*16 + k
    float acc = 0.f;
    #pragma unroll
    for (int it = 0; it < 24; ++it) acc += s_part[(size_t)it * 131072 + idx];
    acc *= scale;
    float n2 = acc * acc;
    n2 += __shfl_xor(n2, 1, 64);
    n2 += __shfl_xor(n2, 2, 64);
    n2 += __shfl_xor(n2, 4, 64);
    n2 += __shfl_xor(n2, 8, 64);
    float n = sqrtf(n2);
    float val = acc * n / (1.f + n2);
    if (TRANSPOSED) {
        int k = idx & 15, o = (idx >> 4) & 63, b = idx >> 10;
        v[((size_t)o * 128 + b) * 16 + k] = val;
    } else {
        v[idx] = val;
    }
}

// ---------------- b-pass (32x32x16 MFMA, K=16 exact), W staged via LDS transposed.
// ILP restructure: per (mt,nt) all u/blog loads issue BEFORE the MFMA cluster (one
// latency), dots after one wait; g-writes split across kh halves (full 64-lane stores).
template <bool ACCUM>
__global__ __launch_bounds__(256, 4) void bpass_kernel(
    const float* __restrict__ W, const float* __restrict__ u2,
    const float* __restrict__ v_t, float* __restrict__ blog) {
    int o = blockIdx.x, it = blockIdx.y;   // it: 0..23 (32 caps)
    int tid = threadIdx.x;
    int wv = tid >> 6;
    int l = tid & 63;
    int r = l & 31;
    int kh = l >> 5;
    int capB = it * 32;
    __shared__ float wl[32 * 164];
    // stage W tile (32 caps x 128) coalesced, store transposed [cl][d][k]
    #pragma unroll
    for (int itr = 0; itr < 4; ++itr) {
        int F = tid + 256 * itr;           // 0..1023 float4s
        int cap = F >> 5, slot = F & 31;
        int k = slot >> 1, dh = slot & 1;
        float4 t4 = *(const float4*)(W + ((size_t)(capB + cap) * 64 + o) * 128 + k * 8 + dh * 4);
        float* dst = wl + cap * 164 + (dh * 4) * 20 + k;
        dst[0] = t4.x; dst[20] = t4.y; dst[40] = t4.z; dst[60] = t4.w;
    }
    // hoist B-frags (v) — coalesced from v_t[o][b][16]
    bfrag vhi[4], vlo[4];
    #pragma unroll
    for (int nt = 0; nt < 4; ++nt) {
        const float* vp = v_t + ((size_t)o * 128 + nt * 32 + r) * 16 + kh * 8;
        float vv8[8];
        *(float4*)(vv8) = *(const float4*)vp;
        *(float4*)(vv8 + 4) = *(const float4*)(vp + 4);
        split8(vv8, vhi[nt], vlo[nt]);
    }
    __syncthreads();
    #pragma unroll
    for (int mt = 0; mt < 2; ++mt) {
        int cl = wv * 8 + mt * 4 + (r >> 3);
        const float* ap = wl + cl * 164 + (r & 7) * 20 + kh * 8;
        float a8[8];
        *(float4*)(a8) = *(const float4*)ap;
        *(float4*)(a8 + 4) = *(const float4*)(ap + 4);
        bfrag ahi, alo;
        split8(a8, ahi, alo);
        int capg = capB + wv * 8 + mt * 4;
        #pragma unroll
        for (int nt = 0; nt < 4; ++nt) {
            int b = nt * 32 + r;
            // ---- batch all global loads for this (mt,nt)
            float4 u4[4];
            #pragma unroll
            for (int g = 0; g < 4; ++g)
                u4[g] = *(const float4*)(u2 + ((size_t)((capg + g) * 2 + kh) * 128 + b) * 4);
            float prev[2] = {0.f, 0.f};
            int gw = kh * 2;               // this half-wave writes g = gw, gw+1
            if (ACCUM) {
                #pragma unroll
                for (int gg = 0; gg < 2; ++gg)
                    prev[gg] = blog[((size_t)o * 768 + capg + gw + gg) * 128 + b];
            }
            // ---- MFMA cluster (runs while loads are in flight)
            f32x16 acc;
            #pragma unroll
            for (int z = 0; z < 16; ++z) acc[z] = 0.f;
            acc = __builtin_amdgcn_mfma_f32_32x32x16_bf16(ahi, vhi[nt], acc, 0, 0, 0);
            acc = __builtin_amdgcn_mfma_f32_32x32x16_bf16(ahi, vlo[nt], acc, 0, 0, 0);
            acc = __builtin_amdgcn_mfma_f32_32x32x16_bf16(alo, vhi[nt], acc, 0, 0, 0);
            // ---- dots + cross-half sums
            float full[4];
            #pragma unroll
            for (int g = 0; g < 4; ++g) {
                float part = u4[g].x * acc[g * 4 + 0] + u4[g].y * acc[g * 4 + 1]
                           + u4[g].z * acc[g * 4 + 2] + u4[g].w * acc[g * 4 + 3];
                full[g] = part + __shfl_xor(part, 32, 64);
            }
            // ---- full-wave stores: kh=0 writes g 0..1, kh=1 writes g 2..3
            #pragma unroll
            for (int gg = 0; gg < 2; ++gg) {
                int g = gw + gg;
                size_t bi = ((size_t)o * 768 + capg + g) * 128 + b;
                blog[bi] = (ACCUM ? prev[gg] : 0.f) + full[g];
            }
        }
    }
}

extern "C" void kernel_launch(void* const* d_in, const int* in_sizes, int n_in,
                              void* d_out, int out_size, void* d_ws, size_t ws_size,
                              hipStream_t stream) {
    const float* x  = (const float*)d_in[0];
    const float* w1 = (const float*)d_in[1];
    const float* b1 = (const float*)d_in[2];
    const float* wp = (const float*)d_in[3];
    const float* bp = (const float*)d_in[4];
    const float* W  = (const float*)d_in[5];
    float* out = (float*)d_out;
    float* ws = (float*)d_ws;

    float* u2     = ws;                  // 786432
    float* blog   = ws + 786432;         // 6291456
    float* m_     = ws + 7077888;        // 98304
    float* z_     = ws + 7176192;        // 98304
    float* v      = ws + 7274496;        // 131072
    float* s_part = ws + 7405568;        // 3145728 (ends at 10551296 floats = 42.2 MB)
    float* B2     = s_part;              // 884736, dead before spass writes s_part
    float* h1     = s_part + 884736;     // 479232, dead before spass

    conv1_kernel<<<1872, 256, 0, stream>>>(x, w1, b1, h1);
    im2col_kernel<<<432, 256, 0, stream>>>(h1, B2);
    pc_gemm_kernel<<<dim3(192, 4), 256, 0, stream>>>(wp, bp, B2, u2);

    // iteration 0: c uniform (1/64 folded into squash scale)
    spass_kernel<true><<<dim3(64, 24), 256, 0, stream>>>(W, u2, nullptr, nullptr, nullptr, s_part);
    squashv_kernel<true><<<512, 256, 0, stream>>>(s_part, v, 1.f / 64.f);
    bpass_kernel<false><<<dim3(64, 24), 256, 0, stream>>>(W, u2, v, blog);

    // iteration 1 (softmax fused into spass via mz stats)
    mz_kernel<<<768, 128, 0, stream>>>(blog, m_, z_);
    spass_kernel<false><<<dim3(64, 24), 256, 0, stream>>>(W, u2, blog, m_, z_, s_part);
    squashv_kernel<true><<<512, 256, 0, stream>>>(s_part, v, 1.f);
    bpass_kernel<true><<<dim3(64, 24), 256, 0, stream>>>(W, u2, v, blog);

    // final
    mz_kernel<<<768, 128, 0, stream>>>(blog, m_, z_);
    spass_kernel<false><<<dim3(64, 24), 256, 0, stream>>>(W, u2, blog, m_, z_, s_part);
    squashv_kernel<false><<<512, 256, 0, stream>>>(s_part, out, 1.f);
}

// Round 9
// 162.560 us; speedup vs baseline: 1.3621x; 1.0582x over previous
//
#include <hip/hip_runtime.h>
#include <math.h>

#define BATCH 128
#define NCI 768
#define NCO 64
#define DIN 8
#define DOUT 16

typedef __attribute__((ext_vector_type(8))) short bfrag;    // 8 bf16 = 4 VGPR
typedef __attribute__((ext_vector_type(4))) float f32x4;    // 16x16 accumulator
typedef __attribute__((ext_vector_type(16))) float f32x16;  // 32x32 accumulator

// split 8 f32 into bf16 hi (truncation) + bf16 lo (truncation of remainder).
// x = hi + lo with |err| ~ 2^-16 |x|; 3-term MFMA (hh + hl + lh) ~ fp32 precision.
__device__ __forceinline__ void split8(const float* x, bfrag& hi, bfrag& lo) {
    #pragma unroll
    for (int j = 0; j < 8; ++j) {
        unsigned xb = __float_as_uint(x[j]);
        unsigned hb = xb & 0xffff0000u;
        float lf = x[j] - __uint_as_float(hb);
        hi[j] = (short)(xb >> 16);
        lo[j] = (short)(__float_as_uint(lf) >> 16);
    }
}

// ---------------- conv1: x(128,3,32,42) w(32,3,6,6) stride 3 -> h1(128,32,9,13), relu
__global__ __launch_bounds__(256) void conv1_kernel(
    const float* __restrict__ x, const float* __restrict__ w,
    const float* __restrict__ bias, float* __restrict__ h1) {
    __shared__ float wl[32 * 3 * 36];
    for (int i = threadIdx.x; i < 3456; i += 256) wl[i] = w[i];
    __syncthreads();
    int idx = blockIdx.x * 256 + threadIdx.x;
    const int total = BATCH * 32 * 9 * 13;
    if (idx >= total) return;
    int ow = idx % 13; int t = idx / 13;
    int oh = t % 9; t /= 9;
    int oc = t % 32; int b = t / 32;
    float acc = bias[oc];
    const float* xb = x + (size_t)b * 3 * 32 * 42;
    #pragma unroll
    for (int ic = 0; ic < 3; ++ic) {
        const float* xc = xb + ic * 32 * 42 + (oh * 3) * 42 + ow * 3;
        const float* wc = wl + (oc * 3 + ic) * 36;
        #pragma unroll
        for (int kh = 0; kh < 6; ++kh)
            #pragma unroll
            for (int kw = 0; kw < 6; ++kw)
                acc += xc[kh * 42 + kw] * wc[kh * 6 + kw];
    }
    h1[idx] = fmaxf(acc, 0.f);
}

// ---------------- im2col for primary-caps conv: B2[ko][n][j], ko=K-octet (36), n=(b,s) (3072)
__global__ __launch_bounds__(256) void im2col_kernel(
    const float* __restrict__ h1, float* __restrict__ B2) {
    int idx = blockIdx.x * 256 + threadIdx.x;
    if (idx >= 36 * 3072) return;
    int n = idx % 3072, ko = idx / 3072;
    int b = n / 24, s = n % 24, h = s / 6, w = s % 6;
    const float* hb = h1 + (size_t)b * 3744 + (2 * h) * 13 + 2 * w;
    float out[8];
    #pragma unroll
    for (int j = 0; j < 8; ++j) {
        int k = ko * 8 + j;
        int ic = k / 9, r = k % 9;
        int kh = r / 3, kw = r % 3;
        out[j] = hb[ic * 117 + kh * 13 + kw];
    }
    *(float4*)(B2 + (size_t)idx * 8) = *(const float4*)out;
    *(float4*)(B2 + (size_t)idx * 8 + 4) = *(const float4*)(out + 4);
}

// ---------------- pc GEMM (MFMA) + bias + squash -> u2[i][dh][b][4]  (d-half-major)
__global__ __launch_bounds__(256) void pc_gemm_kernel(
    const float* __restrict__ wpc, const float* __restrict__ bias,
    const float* __restrict__ B2, float* __restrict__ u2) {
    int wv = threadIdx.x >> 6;
    int l = threadIdx.x & 63;
    int q = l >> 4, r16 = l & 15;
    int c2t = blockIdx.y * 4 + wv;
    int n0 = blockIdx.x * 16;
    f32x4 acc = {0.f, 0.f, 0.f, 0.f};
    int c2a = c2t * 16 + r16;
    const float* ap0 = wpc + (size_t)c2a * 288 + q * 8;
    const float* bp0 = B2 + ((size_t)q * 3072 + n0 + r16) * 8;
    #pragma unroll
    for (int ks = 0; ks < 9; ++ks) {
        float av[8], bv[8];
        *(float4*)av = *(const float4*)(ap0 + ks * 32);
        *(float4*)(av + 4) = *(const float4*)(ap0 + ks * 32 + 4);
        *(float4*)bv = *(const float4*)(bp0 + (size_t)ks * 4 * 3072 * 8);
        *(float4*)(bv + 4) = *(const float4*)(bp0 + (size_t)ks * 4 * 3072 * 8 + 4);
        bfrag ahi, alo, bhi, blo;
        split8(av, ahi, alo);
        split8(bv, bhi, blo);
        acc = __builtin_amdgcn_mfma_f32_16x16x32_bf16(ahi, bhi, acc, 0, 0, 0);
        acc = __builtin_amdgcn_mfma_f32_16x16x32_bf16(ahi, blo, acc, 0, 0, 0);
        acc = __builtin_amdgcn_mfma_f32_16x16x32_bf16(alo, bhi, acc, 0, 0, 0);
    }
    int n = n0 + r16;
    int b = n / 24, s = n % 24;
    float vals[4], n2[4];
    #pragma unroll
    for (int r = 0; r < 4; ++r) {
        float xv = acc[r] + bias[c2t * 16 + q * 4 + r];
        vals[r] = xv;
        n2[r] = xv * xv;
    }
    #pragma unroll
    for (int r = 0; r < 4; ++r) {
        n2[r] += __shfl_xor(n2[r], 1, 64);
        n2[r] += __shfl_xor(n2[r], 2, 64);
        n2[r] += __shfl_xor(n2[r], 4, 64);
    }
    #pragma unroll
    for (int r = 0; r < 4; ++r) {
        int c2 = c2t * 16 + q * 4 + r;
        int cap = c2 * 3 + (s >> 3);
        int d = s & 7;
        float nr = sqrtf(n2[r]);
        u2[((size_t)(cap * 2 + (d >> 2)) * 128 + b) * 4 + (d & 3)]
            = vals[r] * nr / (1.f + n2[r]);
    }
}

// ---------------- mz: per (i,b) softmax stats over o: m = max, z = 1/sum(exp(.-m))
__global__ __launch_bounds__(128) void mz_kernel(
    const float* __restrict__ blog, float* __restrict__ m_, float* __restrict__ z_) {
    int i = blockIdx.x;
    int b = threadIdx.x;
    const float* src = blog + (size_t)i * 128 + b;
    float r[64];
    float m = -1e30f;
    #pragma unroll
    for (int o = 0; o < 64; ++o) {
        r[o] = src[(size_t)o * 98304];
        m = fmaxf(m, r[o]);
    }
    float sum = 0.f;
    #pragma unroll
    for (int o = 0; o < 64; ++o) sum += __expf(r[o] - m);
    m_[i * 128 + b] = m;
    z_[i * 128 + b] = 1.f / sum;
}

// ---------------- s-pass (MFMA), software-pipelined: per (o, it of 32 caps).
// Step s (=0..7): cap = i0 + s*4 + q. Loads of step s+1 issue before compute of s.
template <bool UNIFORM>
__global__ __launch_bounds__(256, 4) void spass_kernel(
    const float* __restrict__ W, const float* __restrict__ u2,
    const float* __restrict__ blog, const float* __restrict__ m_,
    const float* __restrict__ z_, float* __restrict__ s_part) {
    int o = blockIdx.x;
    int it = blockIdx.y;       // 0..23 (32 caps)
    int wv = threadIdx.x >> 6;
    int l = threadIdx.x & 63;
    int q = l >> 4, r16 = l & 15;
    int i0 = it * 32;
    f32x4 acc0 = {0.f, 0.f, 0.f, 0.f};
    f32x4 acc1 = {0.f, 0.f, 0.f, 0.f};

    float4 w0[2], w1[2];
    float4 ua[2][2][2];
    float bl[2][2], mv[2][2], zv[2][2];

    auto issue = [&](int s, int buf) {
        int cap = i0 + s * 4 + q;
        const float* wp = W + ((size_t)cap * 64 + o) * 128 + r16 * 8;
        w0[buf] = *(const float4*)wp;
        w1[buf] = *(const float4*)(wp + 4);
        #pragma unroll
        for (int m = 0; m < 2; ++m) {
            int b = wv * 32 + m * 16 + r16;
            ua[buf][m][0] = *(const float4*)(u2 + ((size_t)(cap * 2 + 0) * 128 + b) * 4);
            ua[buf][m][1] = *(const float4*)(u2 + ((size_t)(cap * 2 + 1) * 128 + b) * 4);
            if (!UNIFORM) {
                bl[buf][m] = blog[((size_t)o * 768 + cap) * 128 + b];
                mv[buf][m] = m_[cap * 128 + b];
                zv[buf][m] = z_[cap * 128 + b];
            }
        }
    };

    issue(0, 0);
    #pragma unroll
    for (int s = 0; s < 8; ++s) {
        int cur = s & 1, nxt = cur ^ 1;
        if (s < 7) issue(s + 1, nxt);
        float wv8[8];
        *(float4*)(wv8) = w0[cur];
        *(float4*)(wv8 + 4) = w1[cur];
        bfrag bhi, blo;
        split8(wv8, bhi, blo);
        #pragma unroll
        for (int m = 0; m < 2; ++m) {
            float uv[8];
            *(float4*)(uv) = ua[cur][m][0];
            *(float4*)(uv + 4) = ua[cur][m][1];
            if (!UNIFORM) {
                float c = __expf(bl[cur][m] - mv[cur][m]) * zv[cur][m];
                #pragma unroll
                for (int j = 0; j < 8; ++j) uv[j] *= c;
            }
            bfrag ahi, alo;
            split8(uv, ahi, alo);
            if (m == 0) {
                acc0 = __builtin_amdgcn_mfma_f32_16x16x32_bf16(ahi, bhi, acc0, 0, 0, 0);
                acc0 = __builtin_amdgcn_mfma_f32_16x16x32_bf16(ahi, blo, acc0, 0, 0, 0);
                acc0 = __builtin_amdgcn_mfma_f32_16x16x32_bf16(alo, bhi, acc0, 0, 0, 0);
            } else {
                acc1 = __builtin_amdgcn_mfma_f32_16x16x32_bf16(ahi, bhi, acc1, 0, 0, 0);
                acc1 = __builtin_amdgcn_mfma_f32_16x16x32_bf16(ahi, blo, acc1, 0, 0, 0);
                acc1 = __builtin_amdgcn_mfma_f32_16x16x32_bf16(alo, bhi, acc1, 0, 0, 0);
            }
        }
    }
    #pragma unroll
    for (int reg = 0; reg < 4; ++reg) {
        int b0 = wv * 32 + q * 4 + reg;
        s_part[(((size_t)it * 128 + b0) * 64 + o) * 16 + r16] = acc0[reg];
        int b1 = b0 + 16;
        s_part[(((size_t)it * 128 + b1) * 64 + o) * 16 + r16] = acc1[reg];
    }
}

// ---------------- reduce partials + squash -> v ([b][o][k] for output, [o][b][k] for bpass)
template <bool TRANSPOSED>
__global__ __launch_bounds__(256) void squashv_kernel(
    const float* __restrict__ s_part, float* __restrict__ v, float scale) {
    int idx = blockIdx.x * 256 + threadIdx.x;  // b*1024 + o*16 + k
    float acc = 0.f;
    #pragma unroll
    for (int it = 0; it < 24; ++it) acc += s_part[(size_t)it * 131072 + idx];
    acc *= scale;
    float n2 = acc * acc;
    n2 += __shfl_xor(n2, 1, 64);
    n2 += __shfl_xor(n2, 2, 64);
    n2 += __shfl_xor(n2, 4, 64);
    n2 += __shfl_xor(n2, 8, 64);
    float n = sqrtf(n2);
    float val = acc * n / (1.f + n2);
    if (TRANSPOSED) {
        int k = idx & 15, o = (idx >> 4) & 63, b = idx >> 10;
        v[((size_t)o * 128 + b) * 16 + k] = val;
    } else {
        v[idx] = val;
    }
}

// ---------------- b-pass (32x32x16 MFMA, K=16 exact), W staged via LDS transposed.
// Per mt: ALL nt u-loads + prev-blog loads issue before the MFMA clusters.
template <bool ACCUM>
__global__ __launch_bounds__(256, 4) void bpass_kernel(
    const float* __restrict__ W, const float* __restrict__ u2,
    const float* __restrict__ v_t, float* __restrict__ blog) {
    int o = blockIdx.x, it = blockIdx.y;   // it: 0..23 (32 caps)
    int tid = threadIdx.x;
    int wv = tid >> 6;
    int l = tid & 63;
    int r = l & 31;
    int kh = l >> 5;
    int capB = it * 32;
    __shared__ float wl[32 * 164];
    // stage W tile (32 caps x 128) coalesced, store transposed [cl][d][k]
    #pragma unroll
    for (int itr = 0; itr < 4; ++itr) {
        int F = tid + 256 * itr;           // 0..1023 float4s
        int cap = F >> 5, slot = F & 31;
        int k = slot >> 1, dh = slot & 1;
        float4 t4 = *(const float4*)(W + ((size_t)(capB + cap) * 64 + o) * 128 + k * 8 + dh * 4);
        float* dst = wl + cap * 164 + (dh * 4) * 20 + k;
        dst[0] = t4.x; dst[20] = t4.y; dst[40] = t4.z; dst[60] = t4.w;
    }
    // hoist B-frags (v) — coalesced from v_t[o][b][16]
    bfrag vhi[4], vlo[4];
    #pragma unroll
    for (int nt = 0; nt < 4; ++nt) {
        const float* vp = v_t + ((size_t)o * 128 + nt * 32 + r) * 16 + kh * 8;
        float vv8[8];
        *(float4*)(vv8) = *(const float4*)vp;
        *(float4*)(vv8 + 4) = *(const float4*)(vp + 4);
        split8(vv8, vhi[nt], vlo[nt]);
    }
    __syncthreads();
    #pragma unroll
    for (int mt = 0; mt < 2; ++mt) {
        int cl = wv * 8 + mt * 4 + (r >> 3);
        const float* ap = wl + cl * 164 + (r & 7) * 20 + kh * 8;
        float a8[8];
        *(float4*)(a8) = *(const float4*)ap;
        *(float4*)(a8 + 4) = *(const float4*)(ap + 4);
        int capg = capB + wv * 8 + mt * 4;
        int gw = kh * 2;                   // this half-wave writes g = gw, gw+1
        // ---- issue ALL global loads for this mt (independent of LDS/MFMA)
        float4 u4[4][4];
        #pragma unroll
        for (int nt = 0; nt < 4; ++nt) {
            int b = nt * 32 + r;
            #pragma unroll
            for (int g = 0; g < 4; ++g)
                u4[nt][g] = *(const float4*)(u2 + ((size_t)((capg + g) * 2 + kh) * 128 + b) * 4);
        }
        float prevv[4][2];
        if (ACCUM) {
            #pragma unroll
            for (int nt = 0; nt < 4; ++nt) {
                int b = nt * 32 + r;
                #pragma unroll
                for (int gg = 0; gg < 2; ++gg)
                    prevv[nt][gg] = blog[((size_t)o * 768 + capg + gw + gg) * 128 + b];
            }
        }
        bfrag ahi, alo;
        split8(a8, ahi, alo);
        #pragma unroll
        for (int nt = 0; nt < 4; ++nt) {
            int b = nt * 32 + r;
            f32x16 acc;
            #pragma unroll
            for (int z = 0; z < 16; ++z) acc[z] = 0.f;
            acc = __builtin_amdgcn_mfma_f32_32x32x16_bf16(ahi, vhi[nt], acc, 0, 0, 0);
            acc = __builtin_amdgcn_mfma_f32_32x32x16_bf16(ahi, vlo[nt], acc, 0, 0, 0);
            acc = __builtin_amdgcn_mfma_f32_32x32x16_bf16(alo, vhi[nt], acc, 0, 0, 0);
            float full[4];
            #pragma unroll
            for (int g = 0; g < 4; ++g) {
                float part = u4[nt][g].x * acc[g * 4 + 0] + u4[nt][g].y * acc[g * 4 + 1]
                           + u4[nt][g].z * acc[g * 4 + 2] + u4[nt][g].w * acc[g * 4 + 3];
                full[g] = part + __shfl_xor(part, 32, 64);
            }
            #pragma unroll
            for (int gg = 0; gg < 2; ++gg) {
                int g = gw + gg;
                size_t bi = ((size_t)o * 768 + capg + g) * 128 + b;
                blog[bi] = (ACCUM ? prevv[nt][gg] : 0.f) + full[g];
            }
        }
    }
}

extern "C" void kernel_launch(void* const* d_in, const int* in_sizes, int n_in,
                              void* d_out, int out_size, void* d_ws, size_t ws_size,
                              hipStream_t stream) {
    const float* x  = (const float*)d_in[0];
    const float* w1 = (const float*)d_in[1];
    const float* b1 = (const float*)d_in[2];
    const float* wp = (const float*)d_in[3];
    const float* bp = (const float*)d_in[4];
    const float* W  = (const float*)d_in[5];
    float* out = (float*)d_out;
    float* ws = (float*)d_ws;

    float* u2     = ws;                  // 786432
    float* blog   = ws + 786432;         // 6291456
    float* m_     = ws + 7077888;        // 98304
    float* z_     = ws + 7176192;        // 98304
    float* v      = ws + 7274496;        // 131072
    float* s_part = ws + 7405568;        // 3145728 (ends at 10551296 floats = 42.2 MB)
    float* B2     = s_part;              // 884736, dead before spass writes s_part
    float* h1     = s_part + 884736;     // 479232, dead before spass

    conv1_kernel<<<1872, 256, 0, stream>>>(x, w1, b1, h1);
    im2col_kernel<<<432, 256, 0, stream>>>(h1, B2);
    pc_gemm_kernel<<<dim3(192, 4), 256, 0, stream>>>(wp, bp, B2, u2);

    // iteration 0: c uniform (1/64 folded into squash scale)
    spass_kernel<true><<<dim3(64, 24), 256, 0, stream>>>(W, u2, nullptr, nullptr, nullptr, s_part);
    squashv_kernel<true><<<512, 256, 0, stream>>>(s_part, v, 1.f / 64.f);
    bpass_kernel<false><<<dim3(64, 24), 256, 0, stream>>>(W, u2, v, blog);

    // iteration 1 (softmax fused into spass via mz stats)
    mz_kernel<<<768, 128, 0, stream>>>(blog, m_, z_);
    spass_kernel<false><<<dim3(64, 24), 256, 0, stream>>>(W, u2, blog, m_, z_, s_part);
    squashv_kernel<true><<<512, 256, 0, stream>>>(s_part, v, 1.f);
    bpass_kernel<true><<<dim3(64, 24), 256, 0, stream>>>(W, u2, v, blog);

    // final
    mz_kernel<<<768, 128, 0, stream>>>(blog, m_, z_);
    spass_kernel<false><<<dim3(64, 24), 256, 0, stream>>>(W, u2, blog, m_, z_, s_part);
    squashv_kernel<false><<<512, 256, 0, stream>>>(s_part, out, 1.f);
}

// Round 10
// 160.635 us; speedup vs baseline: 1.3784x; 1.0120x over previous
//
#include <hip/hip_runtime.h>
#include <math.h>

#define BATCH 128
#define NCI 768
#define NCO 64
#define DIN 8
#define DOUT 16

typedef __attribute__((ext_vector_type(8))) short bfrag;    // 8 bf16 = 4 VGPR
typedef __attribute__((ext_vector_type(4))) float f32x4;    // 16x16 accumulator
typedef __attribute__((ext_vector_type(16))) float f32x16;  // 32x32 accumulator

// split 8 f32 into bf16 hi (truncation) + bf16 lo (truncation of remainder).
// x = hi + lo with |err| ~ 2^-16 |x|; 3-term MFMA (hh + hl + lh) ~ fp32 precision.
__device__ __forceinline__ void split8(const float* x, bfrag& hi, bfrag& lo) {
    #pragma unroll
    for (int j = 0; j < 8; ++j) {
        unsigned xb = __float_as_uint(x[j]);
        unsigned hb = xb & 0xffff0000u;
        float lf = x[j] - __uint_as_float(hb);
        hi[j] = (short)(xb >> 16);
        lo[j] = (short)(__float_as_uint(lf) >> 16);
    }
}

// ---------------- conv1: x(128,3,32,42) w(32,3,6,6) stride 3 -> h1(128,32,9,13), relu
__global__ __launch_bounds__(256) void conv1_kernel(
    const float* __restrict__ x, const float* __restrict__ w,
    const float* __restrict__ bias, float* __restrict__ h1) {
    __shared__ float wl[32 * 3 * 36];
    for (int i = threadIdx.x; i < 3456; i += 256) wl[i] = w[i];
    __syncthreads();
    int idx = blockIdx.x * 256 + threadIdx.x;
    const int total = BATCH * 32 * 9 * 13;
    if (idx >= total) return;
    int ow = idx % 13; int t = idx / 13;
    int oh = t % 9; t /= 9;
    int oc = t % 32; int b = t / 32;
    float acc = bias[oc];
    const float* xb = x + (size_t)b * 3 * 32 * 42;
    #pragma unroll
    for (int ic = 0; ic < 3; ++ic) {
        const float* xc = xb + ic * 32 * 42 + (oh * 3) * 42 + ow * 3;
        const float* wc = wl + (oc * 3 + ic) * 36;
        #pragma unroll
        for (int kh = 0; kh < 6; ++kh)
            #pragma unroll
            for (int kw = 0; kw < 6; ++kw)
                acc += xc[kh * 42 + kw] * wc[kh * 6 + kw];
    }
    h1[idx] = fmaxf(acc, 0.f);
}

// ---------------- im2col for primary-caps conv: B2[ko][n][j], ko=K-octet (36), n=(b,s) (3072)
__global__ __launch_bounds__(256) void im2col_kernel(
    const float* __restrict__ h1, float* __restrict__ B2) {
    int idx = blockIdx.x * 256 + threadIdx.x;
    if (idx >= 36 * 3072) return;
    int n = idx % 3072, ko = idx / 3072;
    int b = n / 24, s = n % 24, h = s / 6, w = s % 6;
    const float* hb = h1 + (size_t)b * 3744 + (2 * h) * 13 + 2 * w;
    float out[8];
    #pragma unroll
    for (int j = 0; j < 8; ++j) {
        int k = ko * 8 + j;
        int ic = k / 9, r = k % 9;
        int kh = r / 3, kw = r % 3;
        out[j] = hb[ic * 117 + kh * 13 + kw];
    }
    *(float4*)(B2 + (size_t)idx * 8) = *(const float4*)out;
    *(float4*)(B2 + (size_t)idx * 8 + 4) = *(const float4*)(out + 4);
}

// ---------------- pc GEMM (MFMA) + bias + squash -> u2[i][dh][b][4]  (d-half-major)
__global__ __launch_bounds__(256) void pc_gemm_kernel(
    const float* __restrict__ wpc, const float* __restrict__ bias,
    const float* __restrict__ B2, float* __restrict__ u2) {
    int wv = threadIdx.x >> 6;
    int l = threadIdx.x & 63;
    int q = l >> 4, r16 = l & 15;
    int c2t = blockIdx.y * 4 + wv;
    int n0 = blockIdx.x * 16;
    f32x4 acc = {0.f, 0.f, 0.f, 0.f};
    int c2a = c2t * 16 + r16;
    const float* ap0 = wpc + (size_t)c2a * 288 + q * 8;
    const float* bp0 = B2 + ((size_t)q * 3072 + n0 + r16) * 8;
    #pragma unroll
    for (int ks = 0; ks < 9; ++ks) {
        float av[8], bv[8];
        *(float4*)av = *(const float4*)(ap0 + ks * 32);
        *(float4*)(av + 4) = *(const float4*)(ap0 + ks * 32 + 4);
        *(float4*)bv = *(const float4*)(bp0 + (size_t)ks * 4 * 3072 * 8);
        *(float4*)(bv + 4) = *(const float4*)(bp0 + (size_t)ks * 4 * 3072 * 8 + 4);
        bfrag ahi, alo, bhi, blo;
        split8(av, ahi, alo);
        split8(bv, bhi, blo);
        acc = __builtin_amdgcn_mfma_f32_16x16x32_bf16(ahi, bhi, acc, 0, 0, 0);
        acc = __builtin_amdgcn_mfma_f32_16x16x32_bf16(ahi, blo, acc, 0, 0, 0);
        acc = __builtin_amdgcn_mfma_f32_16x16x32_bf16(alo, bhi, acc, 0, 0, 0);
    }
    int n = n0 + r16;
    int b = n / 24, s = n % 24;
    float vals[4], n2[4];
    #pragma unroll
    for (int r = 0; r < 4; ++r) {
        float xv = acc[r] + bias[c2t * 16 + q * 4 + r];
        vals[r] = xv;
        n2[r] = xv * xv;
    }
    #pragma unroll
    for (int r = 0; r < 4; ++r) {
        n2[r] += __shfl_xor(n2[r], 1, 64);
        n2[r] += __shfl_xor(n2[r], 2, 64);
        n2[r] += __shfl_xor(n2[r], 4, 64);
    }
    #pragma unroll
    for (int r = 0; r < 4; ++r) {
        int c2 = c2t * 16 + q * 4 + r;
        int cap = c2 * 3 + (s >> 3);
        int d = s & 7;
        float nr = sqrtf(n2[r]);
        u2[((size_t)(cap * 2 + (d >> 2)) * 128 + b) * 4 + (d & 3)]
            = vals[r] * nr / (1.f + n2[r]);
    }
}

// ---------------- mz: per (i,b) softmax stats over o: m = max, z = 1/sum(exp(.-m))
__global__ __launch_bounds__(128) void mz_kernel(
    const float* __restrict__ blog, float* __restrict__ m_, float* __restrict__ z_) {
    int i = blockIdx.x;
    int b = threadIdx.x;
    const float* src = blog + (size_t)i * 128 + b;
    float r[64];
    float m = -1e30f;
    #pragma unroll
    for (int o = 0; o < 64; ++o) {
        r[o] = src[(size_t)o * 98304];
        m = fmaxf(m, r[o]);
    }
    float sum = 0.f;
    #pragma unroll
    for (int o = 0; o < 64; ++o) sum += __expf(r[o] - m);
    m_[i * 128 + b] = m;
    z_[i * 128 + b] = 1.f / sum;
}

// ---------------- s-pass (MFMA): W staged in LDS (off the per-step chain);
// u/blog loads pipelined 3-deep (issue s+2 during compute s). Prologue u-loads
// issue BEFORE the staging barrier so they overlap the LDS fill.
template <bool UNIFORM>
__global__ __launch_bounds__(256, 4) void spass_kernel(
    const float* __restrict__ W, const float* __restrict__ u2,
    const float* __restrict__ blog, const float* __restrict__ m_,
    const float* __restrict__ z_, float* __restrict__ s_part) {
    int o = blockIdx.x;
    int it = blockIdx.y;       // 0..23 (32 caps)
    int tid = threadIdx.x;
    int wv = tid >> 6;
    int l = tid & 63;
    int q = l >> 4, r16 = l & 15;
    int i0 = it * 32;
    __shared__ float wl[32 * 132];   // +4 pad per cap row

    float4 ua[3][2][2];
    float bl[3][2], mv[3][2], zv[3][2];
    auto issue = [&](int s, int buf) {
        int cap = i0 + s * 4 + q;
        #pragma unroll
        for (int m = 0; m < 2; ++m) {
            int b = wv * 32 + m * 16 + r16;
            ua[buf][m][0] = *(const float4*)(u2 + ((size_t)(cap * 2 + 0) * 128 + b) * 4);
            ua[buf][m][1] = *(const float4*)(u2 + ((size_t)(cap * 2 + 1) * 128 + b) * 4);
            if (!UNIFORM) {
                bl[buf][m] = blog[((size_t)o * 768 + cap) * 128 + b];
                mv[buf][m] = m_[cap * 128 + b];
                zv[buf][m] = z_[cap * 128 + b];
            }
        }
    };

    // prologue loads first (independent of LDS)
    issue(0, 0);
    issue(1, 1);
    // stage W tile: 32 caps x 128 floats, coalesced
    #pragma unroll
    for (int itr = 0; itr < 4; ++itr) {
        int F = tid + 256 * itr;     // 0..1023 float4s
        int cap = F >> 5, slot = F & 31;
        float4 t4 = *(const float4*)(W + ((size_t)(i0 + cap) * 64 + o) * 128 + slot * 4);
        *(float4*)(wl + cap * 132 + slot * 4) = t4;
    }
    __syncthreads();

    f32x4 acc0 = {0.f, 0.f, 0.f, 0.f};
    f32x4 acc1 = {0.f, 0.f, 0.f, 0.f};
    #pragma unroll
    for (int s = 0; s < 8; ++s) {
        int cur = s % 3;
        if (s < 6) issue(s + 2, (s + 2) % 3);
        // W B-frag from LDS
        const float* wp = wl + (s * 4 + q) * 132 + r16 * 8;
        float wv8[8];
        *(float4*)(wv8) = *(const float4*)wp;
        *(float4*)(wv8 + 4) = *(const float4*)(wp + 4);
        bfrag bhi, blo;
        split8(wv8, bhi, blo);
        #pragma unroll
        for (int m = 0; m < 2; ++m) {
            float uv[8];
            *(float4*)(uv) = ua[cur][m][0];
            *(float4*)(uv + 4) = ua[cur][m][1];
            if (!UNIFORM) {
                float c = __expf(bl[cur][m] - mv[cur][m]) * zv[cur][m];
                #pragma unroll
                for (int j = 0; j < 8; ++j) uv[j] *= c;
            }
            bfrag ahi, alo;
            split8(uv, ahi, alo);
            if (m == 0) {
                acc0 = __builtin_amdgcn_mfma_f32_16x16x32_bf16(ahi, bhi, acc0, 0, 0, 0);
                acc0 = __builtin_amdgcn_mfma_f32_16x16x32_bf16(ahi, blo, acc0, 0, 0, 0);
                acc0 = __builtin_amdgcn_mfma_f32_16x16x32_bf16(alo, bhi, acc0, 0, 0, 0);
            } else {
                acc1 = __builtin_amdgcn_mfma_f32_16x16x32_bf16(ahi, bhi, acc1, 0, 0, 0);
                acc1 = __builtin_amdgcn_mfma_f32_16x16x32_bf16(ahi, blo, acc1, 0, 0, 0);
                acc1 = __builtin_amdgcn_mfma_f32_16x16x32_bf16(alo, bhi, acc1, 0, 0, 0);
            }
        }
    }
    #pragma unroll
    for (int reg = 0; reg < 4; ++reg) {
        int b0 = wv * 32 + q * 4 + reg;
        s_part[(((size_t)it * 128 + b0) * 64 + o) * 16 + r16] = acc0[reg];
        int b1 = b0 + 16;
        s_part[(((size_t)it * 128 + b1) * 64 + o) * 16 + r16] = acc1[reg];
    }
}

// ---------------- reduce partials + squash -> v ([b][o][k] for output, [o][b][k] for bpass)
template <bool TRANSPOSED>
__global__ __launch_bounds__(256) void squashv_kernel(
    const float* __restrict__ s_part, float* __restrict__ v, float scale) {
    int idx = blockIdx.x * 256 + threadIdx.x;  // b*1024 + o*16 + k
    float acc = 0.f;
    #pragma unroll
    for (int it = 0; it < 24; ++it) acc += s_part[(size_t)it * 131072 + idx];
    acc *= scale;
    float n2 = acc * acc;
    n2 += __shfl_xor(n2, 1, 64);
    n2 += __shfl_xor(n2, 2, 64);
    n2 += __shfl_xor(n2, 4, 64);
    n2 += __shfl_xor(n2, 8, 64);
    float n = sqrtf(n2);
    float val = acc * n / (1.f + n2);
    if (TRANSPOSED) {
        int k = idx & 15, o = (idx >> 4) & 63, b = idx >> 10;
        v[((size_t)o * 128 + b) * 16 + k] = val;
    } else {
        v[idx] = val;
    }
}

// ---------------- b-pass (32x32x16 MFMA, K=16 exact), W staged via LDS transposed.
// u-loads double-buffered at nt granularity; prev-blog batched per mt.
template <bool ACCUM>
__global__ __launch_bounds__(256, 4) void bpass_kernel(
    const float* __restrict__ W, const float* __restrict__ u2,
    const float* __restrict__ v_t, float* __restrict__ blog) {
    int o = blockIdx.x, it = blockIdx.y;   // it: 0..23 (32 caps)
    int tid = threadIdx.x;
    int wv = tid >> 6;
    int l = tid & 63;
    int r = l & 31;
    int kh = l >> 5;
    int capB = it * 32;
    __shared__ float wl[32 * 164];
    // stage W tile (32 caps x 128) coalesced, store transposed [cl][d][k]
    #pragma unroll
    for (int itr = 0; itr < 4; ++itr) {
        int F = tid + 256 * itr;           // 0..1023 float4s
        int cap = F >> 5, slot = F & 31;
        int k = slot >> 1, dh = slot & 1;
        float4 t4 = *(const float4*)(W + ((size_t)(capB + cap) * 64 + o) * 128 + k * 8 + dh * 4);
        float* dst = wl + cap * 164 + (dh * 4) * 20 + k;
        dst[0] = t4.x; dst[20] = t4.y; dst[40] = t4.z; dst[60] = t4.w;
    }
    // hoist B-frags (v) — coalesced from v_t[o][b][16]
    bfrag vhi[4], vlo[4];
    #pragma unroll
    for (int nt = 0; nt < 4; ++nt) {
        const float* vp = v_t + ((size_t)o * 128 + nt * 32 + r) * 16 + kh * 8;
        float vv8[8];
        *(float4*)(vv8) = *(const float4*)vp;
        *(float4*)(vv8 + 4) = *(const float4*)(vp + 4);
        split8(vv8, vhi[nt], vlo[nt]);
    }
    __syncthreads();
    #pragma unroll
    for (int mt = 0; mt < 2; ++mt) {
        int cl = wv * 8 + mt * 4 + (r >> 3);
        const float* ap = wl + cl * 164 + (r & 7) * 20 + kh * 8;
        float a8[8];
        *(float4*)(a8) = *(const float4*)ap;
        *(float4*)(a8 + 4) = *(const float4*)(ap + 4);
        int capg = capB + wv * 8 + mt * 4;
        int gw = kh * 2;                   // this half-wave writes g = gw, gw+1
        // prev-blog loads for the whole mt
        float prevv[4][2];
        if (ACCUM) {
            #pragma unroll
            for (int nt = 0; nt < 4; ++nt) {
                int b = nt * 32 + r;
                #pragma unroll
                for (int gg = 0; gg < 2; ++gg)
                    prevv[nt][gg] = blog[((size_t)o * 768 + capg + gw + gg) * 128 + b];
            }
        }
        // u double-buffer at nt granularity
        float4 u4b[2][4];
        #pragma unroll
        for (int g = 0; g < 4; ++g)
            u4b[0][g] = *(const float4*)(u2 + ((size_t)((capg + g) * 2 + kh) * 128 + r) * 4);
        bfrag ahi, alo;
        split8(a8, ahi, alo);
        #pragma unroll
        for (int nt = 0; nt < 4; ++nt) {
            int cur = nt & 1;
            if (nt < 3) {
                int bn = (nt + 1) * 32 + r;
                #pragma unroll
                for (int g = 0; g < 4; ++g)
                    u4b[cur ^ 1][g] = *(const float4*)(u2 + ((size_t)((capg + g) * 2 + kh) * 128 + bn) * 4);
            }
            int b = nt * 32 + r;
            f32x16 acc;
            #pragma unroll
            for (int z = 0; z < 16; ++z) acc[z] = 0.f;
            acc = __builtin_amdgcn_mfma_f32_32x32x16_bf16(ahi, vhi[nt], acc, 0, 0, 0);
            acc = __builtin_amdgcn_mfma_f32_32x32x16_bf16(ahi, vlo[nt], acc, 0, 0, 0);
            acc = __builtin_amdgcn_mfma_f32_32x32x16_bf16(alo, vhi[nt], acc, 0, 0, 0);
            float full[4];
            #pragma unroll
            for (int g = 0; g < 4; ++g) {
                float part = u4b[cur][g].x * acc[g * 4 + 0] + u4b[cur][g].y * acc[g * 4 + 1]
                           + u4b[cur][g].z * acc[g * 4 + 2] + u4b[cur][g].w * acc[g * 4 + 3];
                full[g] = part + __shfl_xor(part, 32, 64);
            }
            #pragma unroll
            for (int gg = 0; gg < 2; ++gg) {
                int g = gw + gg;
                size_t bi = ((size_t)o * 768 + capg + g) * 128 + b;
                blog[bi] = (ACCUM ? prevv[nt][gg] : 0.f) + full[g];
            }
        }
    }
}

extern "C" void kernel_launch(void* const* d_in, const int* in_sizes, int n_in,
                              void* d_out, int out_size, void* d_ws, size_t ws_size,
                              hipStream_t stream) {
    const float* x  = (const float*)d_in[0];
    const float* w1 = (const float*)d_in[1];
    const float* b1 = (const float*)d_in[2];
    const float* wp = (const float*)d_in[3];
    const float* bp = (const float*)d_in[4];
    const float* W  = (const float*)d_in[5];
    float* out = (float*)d_out;
    float* ws = (float*)d_ws;

    float* u2     = ws;                  // 786432
    float* blog   = ws + 786432;         // 6291456
    float* m_     = ws + 7077888;        // 98304
    float* z_     = ws + 7176192;        // 98304
    float* v      = ws + 7274496;        // 131072
    float* s_part = ws + 7405568;        // 3145728 (ends at 10551296 floats = 42.2 MB)
    float* B2     = s_part;              // 884736, dead before spass writes s_part
    float* h1     = s_part + 884736;     // 479232, dead before spass

    conv1_kernel<<<1872, 256, 0, stream>>>(x, w1, b1, h1);
    im2col_kernel<<<432, 256, 0, stream>>>(h1, B2);
    pc_gemm_kernel<<<dim3(192, 4), 256, 0, stream>>>(wp, bp, B2, u2);

    // iteration 0: c uniform (1/64 folded into squash scale)
    spass_kernel<true><<<dim3(64, 24), 256, 0, stream>>>(W, u2, nullptr, nullptr, nullptr, s_part);
    squashv_kernel<true><<<512, 256, 0, stream>>>(s_part, v, 1.f / 64.f);
    bpass_kernel<false><<<dim3(64, 24), 256, 0, stream>>>(W, u2, v, blog);

    // iteration 1 (softmax fused into spass via mz stats)
    mz_kernel<<<768, 128, 0, stream>>>(blog, m_, z_);
    spass_kernel<false><<<dim3(64, 24), 256, 0, stream>>>(W, u2, blog, m_, z_, s_part);
    squashv_kernel<true><<<512, 256, 0, stream>>>(s_part, v, 1.f);
    bpass_kernel<true><<<dim3(64, 24), 256, 0, stream>>>(W, u2, v, blog);

    // final
    mz_kernel<<<768, 128, 0, stream>>>(blog, m_, z_);
    spass_kernel<false><<<dim3(64, 24), 256, 0, stream>>>(W, u2, blog, m_, z_, s_part);
    squashv_kernel<false><<<512, 256, 0, stream>>>(s_part, out, 1.f);
}